// Round 4
// baseline (859.480 us; speedup 1.0000x reference)
//
#include <hip/hip_runtime.h>
#include <math.h>

#define NTOK   16384
#define DMODEL 4096
#define NEXP   64
#define WAVES  8
#define TOKS   32                    // tokens per block
#define KSLAB  (DMODEL / WAVES)      // 512 k per wave
#define KC     16                    // k per staged chunk
#define NCH    (KSLAB / KC)          // 32 chunks
#define XSTR   20                    // LDS x-row stride (floats), 16B-aligned, breaks pow2
#define WOFF   (TOKS * XSTR)         // 640
#define WAVE_LDS (WOFF + KC * NEXP)  // 1664 floats per wave region
#define LSTR   68                    // logits row stride (17 float4s)
#define LOGOFF (WAVES * WAVE_LDS)    // 13312

// 4 FMAs: one float4 of W against one x scalar into acc[B..B+3]
#define FMA16(WQ, XV, ACC, B)                         \
    ACC[(B)+0] = fmaf((WQ).x, (XV), ACC[(B)+0]);      \
    ACC[(B)+1] = fmaf((WQ).y, (XV), ACC[(B)+1]);      \
    ACC[(B)+2] = fmaf((WQ).z, (XV), ACC[(B)+2]);      \
    ACC[(B)+3] = fmaf((WQ).w, (XV), ACC[(B)+3]);

// one k-step: 16 experts x 2 tokens = 32 FMAs, W via 4 broadcast b128 reads
#define STEP(WRP, XAV, XBV) do {                      \
    const float* _wr = (WRP);                         \
    float4 w0 = *(const float4*)(_wr);                \
    float4 w1 = *(const float4*)(_wr + 4);            \
    float4 w2 = *(const float4*)(_wr + 8);            \
    float4 w3 = *(const float4*)(_wr + 12);           \
    FMA16(w0, (XAV), acc0, 0)  FMA16(w1, (XAV), acc0, 4)   \
    FMA16(w2, (XAV), acc0, 8)  FMA16(w3, (XAV), acc0, 12)  \
    FMA16(w0, (XBV), acc1, 0)  FMA16(w1, (XBV), acc1, 4)   \
    FMA16(w2, (XBV), acc1, 8)  FMA16(w3, (XBV), acc1, 12)  \
} while (0)

__global__ __launch_bounds__(WAVES * 64, 4)
void router_kernel(const float* __restrict__ x,
                   const float* __restrict__ W,
                   const float* __restrict__ b,
                   float* __restrict__ out)
{
    __shared__ __align__(16) float sh[LOGOFF + TOKS * LSTR]; // 61952 B

    const int lane = threadIdx.x & 63;
    const int wid  = threadIdx.x >> 6;
    const int t0   = blockIdx.x * TOKS;
    const int kb   = __builtin_amdgcn_readfirstlane(wid * KSLAB);

    float* xs = sh + wid * WAVE_LDS;      // [32 tok][XSTR]
    float* ws = xs + WOFF;                // [16 k][64 e] linear
    float* lg = sh + LOGOFF;              // [32 tok][LSTR]

    // ---- staging addresses ----
    // W chunk: 1024 contiguous floats at W + (kb + c*KC)*NEXP
    const float* gw = W + (size_t)kb * NEXP + lane * 4;
    float*       lw = ws + lane * 4;
    // x chunk: 32 rows x 16 cols (64B row segments), 2 float4 per lane
    const int xi1 = 64 + lane;
    const int xr0 = lane >> 2, xq0 = lane & 3;
    const int xr1 = xi1 >> 2,  xq1 = xi1 & 3;
    const float* gx0 = x + (size_t)(t0 + xr0) * DMODEL + kb + xq0 * 4;
    const float* gx1 = x + (size_t)(t0 + xr1) * DMODEL + kb + xq1 * 4;
    float* lx0 = xs + xr0 * XSTR + xq0 * 4;
    float* lx1 = xs + xr1 * XSTR + xq1 * 4;

    // ---- compute-lane mapping ----
    const int tg = lane >> 2;             // token group: tokens 2tg, 2tg+1
    const int eg = lane & 3;              // expert group: experts eg*16..+15
    const float* xr_a = xs + (2 * tg) * XSTR;
    const float* xr_b = xs + (2 * tg + 1) * XSTR;
    const float* wr0  = ws + eg * 16;

    float acc0[16], acc1[16];
#pragma unroll
    for (int i = 0; i < 16; ++i) { acc0[i] = 0.f; acc1[i] = 0.f; }

    // prologue: prefetch chunk 0 into registers
    float4 pw0 = *(const float4*)(gw);
    float4 pw1 = *(const float4*)(gw + 256);
    float4 pw2 = *(const float4*)(gw + 512);
    float4 pw3 = *(const float4*)(gw + 768);
    float4 px0 = *(const float4*)(gx0);
    float4 px1 = *(const float4*)(gx1);

#pragma unroll 1
    for (int c = 0; c < NCH; ++c) {
        // drain prefetched registers into this wave's private LDS chunk
        *(float4*)(lw)       = pw0;
        *(float4*)(lw + 256) = pw1;
        *(float4*)(lw + 512) = pw2;
        *(float4*)(lw + 768) = pw3;
        *(float4*)(lx0)      = px0;
        *(float4*)(lx1)      = px1;
        // issue next chunk's global loads (fly during compute below)
        if (c + 1 < NCH) {
            const float* g = gw + (size_t)(c + 1) * (KC * NEXP);
            pw0 = *(const float4*)(g);
            pw1 = *(const float4*)(g + 256);
            pw2 = *(const float4*)(g + 512);
            pw3 = *(const float4*)(g + 768);
            px0 = *(const float4*)(gx0 + (c + 1) * KC);
            px1 = *(const float4*)(gx1 + (c + 1) * KC);
        }
        // compute 16 k-steps (same-wave DS ops are in-order: RAW via LDS safe)
#pragma unroll
        for (int k4 = 0; k4 < KC; k4 += 4) {
            float4 xa = *(const float4*)(xr_a + k4);
            float4 xb = *(const float4*)(xr_b + k4);
            STEP(wr0 + (k4 + 0) * NEXP, xa.x, xb.x);
            STEP(wr0 + (k4 + 1) * NEXP, xa.y, xb.y);
            STEP(wr0 + (k4 + 2) * NEXP, xa.z, xb.z);
            STEP(wr0 + (k4 + 3) * NEXP, xa.w, xb.w);
        }
    }

    // ---- cross-wave K reduction (wid order = fixed summation order) ----
    for (int r = 0; r < WAVES; ++r) {
        if (wid == r) {
            float* dst0 = lg + (2 * tg) * LSTR + eg * 16;
            float* dst1 = dst0 + LSTR;
            if (r == 0) {
#pragma unroll
                for (int q = 0; q < 4; ++q) {
                    *(float4*)(dst0 + 4 * q) = make_float4(acc0[4*q], acc0[4*q+1], acc0[4*q+2], acc0[4*q+3]);
                    *(float4*)(dst1 + 4 * q) = make_float4(acc1[4*q], acc1[4*q+1], acc1[4*q+2], acc1[4*q+3]);
                }
            } else {
#pragma unroll
                for (int q = 0; q < 4; ++q) {
                    float4 t0v = *(float4*)(dst0 + 4 * q);
                    t0v.x += acc0[4*q]; t0v.y += acc0[4*q+1]; t0v.z += acc0[4*q+2]; t0v.w += acc0[4*q+3];
                    *(float4*)(dst0 + 4 * q) = t0v;
                    float4 t1v = *(float4*)(dst1 + 4 * q);
                    t1v.x += acc1[4*q]; t1v.y += acc1[4*q+1]; t1v.z += acc1[4*q+2]; t1v.w += acc1[4*q+3];
                    *(float4*)(dst1 + 4 * q) = t1v;
                }
            }
        }
        __syncthreads();
    }

    // ---- epilogue: wave 0, one token per lane (32 tokens) ----
    if (wid == 0 && lane < TOKS) {
        const int t = t0 + lane;
        const float* lrow = lg + lane * LSTR;
        float l[NEXP];
        float m = -INFINITY;
#pragma unroll
        for (int e = 0; e < NEXP; ++e) {
            l[e] = lrow[e] + b[e];
            m = fmaxf(m, l[e]);
        }
        float Z = 0.f;
#pragma unroll
        for (int e = 0; e < NEXP; ++e) {
            l[e] = expf(l[e] - m);
            Z += l[e];
        }
        float p1 = -1.f, p2 = -1.f;
        int i1 = 0, i2 = 0;
#pragma unroll
        for (int e = 0; e < NEXP; ++e) {
            const float p = l[e] / Z;
            if (p > p1) { p2 = p1; i2 = i1; p1 = p; i1 = e; }
            else if (p > p2) { p2 = p; i2 = e; }
        }
        const float s = p1 + p2;
        out[2 * t]     = p1 / s;
        out[2 * t + 1] = p2 / s;
        out[2 * NTOK + 2 * t]     = (float)i1;
        out[2 * NTOK + 2 * t + 1] = (float)i2;
    }
}

extern "C" void kernel_launch(void* const* d_in, const int* in_sizes, int n_in,
                              void* d_out, int out_size, void* d_ws, size_t ws_size,
                              hipStream_t stream) {
    const float* x = (const float*)d_in[0];
    const float* W = (const float*)d_in[1];
    const float* b = (const float*)d_in[2];
    float* out = (float*)d_out;
    router_kernel<<<dim3(NTOK / TOKS), dim3(WAVES * 64), 0, stream>>>(x, W, b, out);
}